// Round 7
// baseline (561.491 us; speedup 1.0000x reference)
//
#include <hip/hip_runtime.h>
#include <hip/hip_bf16.h>
#include <stdint.h>

#define T_TOK 2048
#define IDIM  1024
#define HID   4096
#define NE    8
#define BM    128
#define BN    128
#define BK    64
#define RMAX  5120
#define MAXTILES 40
#define BNS   (BN * 72)          // sB buffer elements

typedef __bf16 bf16;
typedef bf16  bf16x8 __attribute__((ext_vector_type(8)));
typedef float f32x4  __attribute__((ext_vector_type(4)));

// ---- workspace layout (byte offsets) ----
#define WS_NTILES   128      // 1 int
#define WS_TILE_E   192      // 64 int
#define WS_TILE_R   448      // 64 int
#define WS_TOK_E    1024     // 2*T int
#define WS_TOK_W    17408    // 2*T float
#define WS_ROW_TOK  33792    // RMAX int (-1 = pad)
#define WS_ROW_W    54272    // RMAX float
#define WS_H        131072   // RMAX * (HID/HC) bf16
#define WS_MIN_FAST ((size_t)WS_H + (size_t)RMAX * (HID / 32) * 2)  // ~1.44 MB

// pack helpers
__device__ inline uint4 pack8(float4 a, float4 b) {
    union { bf16 h[8]; uint4 u; } pk;
    pk.h[0] = (bf16)a.x; pk.h[1] = (bf16)a.y; pk.h[2] = (bf16)a.z; pk.h[3] = (bf16)a.w;
    pk.h[4] = (bf16)b.x; pk.h[5] = (bf16)b.y; pk.h[6] = (bf16)b.z; pk.h[7] = (bf16)b.w;
    return pk.u;
}
__device__ inline uint32_t pack2(float a, float b) {
    union { bf16 h[2]; uint32_t u; } pk;
    pk.h[0] = (bf16)a; pk.h[1] = (bf16)b;
    return pk.u;
}

// ---------------- router (+ fused out-zeroing): one wave per token ---------
__global__ __launch_bounds__(256) void k_router(const float* __restrict__ xs,
                                                const float* __restrict__ Wg,
                                                int* __restrict__ tok_e,
                                                float* __restrict__ tok_w,
                                                float4* __restrict__ out4) {
    // zero the output accumulator (ffn2 atomically adds into it)
    int zbase = blockIdx.x * 256 + threadIdx.x;
#pragma unroll
    for (int i = 0; i < 4; i++)
        out4[zbase + i * (T_TOK / 4 * 256)] = make_float4(0.f, 0.f, 0.f, 0.f);

    __shared__ float sWg[NE * IDIM];
    for (int i = threadIdx.x; i < NE * IDIM; i += 256) sWg[i] = Wg[i];
    __syncthreads();
    int wave = threadIdx.x >> 6, lane = threadIdx.x & 63;
    int t = blockIdx.x * 4 + wave;
    if (t >= T_TOK) return;
    float p[NE];
#pragma unroll
    for (int e = 0; e < NE; e++) p[e] = 0.f;
    for (int j = 0; j < IDIM / 64; j++) {
        float x = xs[(size_t)t * IDIM + j * 64 + lane];
#pragma unroll
        for (int e = 0; e < NE; e++)
            p[e] += x * sWg[e * IDIM + j * 64 + lane];
    }
#pragma unroll
    for (int e = 0; e < NE; e++) {
        float v = p[e];
        for (int off = 32; off > 0; off >>= 1) v += __shfl_down(v, off);
        p[e] = v;
    }
    if (lane == 0) {
        int e0 = 0; float l0 = p[0];
        for (int e = 1; e < NE; e++) if (p[e] > l0) { l0 = p[e]; e0 = e; }
        int e1 = -1; float l1 = -1e30f;
        for (int e = 0; e < NE; e++) if (e != e0 && p[e] > l1) { l1 = p[e]; e1 = e; }
        if (e1 < 0) e1 = (e0 + 1) & 7;
        float z = __expf(l1 - l0);              // <= 1
        tok_e[2 * t]     = e0;  tok_e[2 * t + 1] = e1;
        tok_w[2 * t]     = 1.f / (1.f + z);
        tok_w[2 * t + 1] = z / (1.f + z);
    }
}

// ---------------- setup: count + plan + scatter, one block -----------------
__global__ __launch_bounds__(256) void k_setup(int* __restrict__ w,
                                               float* __restrict__ wf) {
    __shared__ int cnt[NE];
    __shared__ int cur[NE];
    int tid = threadIdx.x;
    if (tid < NE) cnt[tid] = 0;
    for (int i = tid; i < RMAX; i += 256) w[WS_ROW_TOK / 4 + i] = -1;
    __syncthreads();
    for (int i = tid; i < 2 * T_TOK; i += 256)
        atomicAdd(&cnt[w[WS_TOK_E / 4 + i]], 1);
    __syncthreads();
    if (tid == 0) {
        int off = 0, nt = 0;
        for (int e = 0; e < NE; e++) {
            cur[e] = off;
            int nb = (cnt[e] + BM - 1) / BM;
            for (int b = 0; b < nb && nt < MAXTILES; b++) {
                w[WS_TILE_E / 4 + nt] = e;
                w[WS_TILE_R / 4 + nt] = off + b * BM;
                nt++;
            }
            off += nb * BM;
        }
        w[WS_NTILES / 4] = nt;
    }
    __syncthreads();
    for (int i = tid; i < 2 * T_TOK; i += 256) {
        int e   = w[WS_TOK_E / 4 + i];
        int pos = atomicAdd(&cur[e], 1);
        if (pos < RMAX) {
            w[WS_ROW_TOK / 4 + pos] = i >> 1;
            wf[WS_ROW_W / 4 + pos]  = wf[WS_TOK_W / 4 + i];
        }
    }
}

// ---------------- FFN1 (pipelined): H = relu(gather(xs) @ W1[e] + b1) ------
__global__ __launch_bounds__(256, 2) void k_ffn1(const float* __restrict__ xs,
                                                 const float* __restrict__ W1,
                                                 const float* __restrict__ b1,
                                                 const int* __restrict__ wsi,
                                                 bf16* __restrict__ H,
                                                 int h0, int CW) {
    int ntiles = wsi[WS_NTILES / 4];
    int tile = blockIdx.y;
    if (tile >= ntiles) return;
    int e    = wsi[WS_TILE_E / 4 + tile];
    int row0 = wsi[WS_TILE_R / 4 + tile];
    int n0l  = blockIdx.x * BN;
    int n0g  = h0 + n0l;

    const int*   row_tok = wsi + WS_ROW_TOK / 4;
    const float* Be      = W1 + (size_t)e * IDIM * HID;
    const float* bias_e  = b1 + (size_t)e * HID;

    __shared__ bf16 sA[BM * BK];          // single buffer
    __shared__ bf16 sB[2][BNS];           // double buffer

    int t    = threadIdx.x;
    int lane = t & 63, wv = t >> 6;
    int wx = wv & 1, wy = wv >> 1;
    int lm = lane & 15, q = lane >> 4;
    int noct0 = t & 15, kp0 = t >> 4;     // B staging coords
    int k8 = (t & 7) * 8;                 // A staging col

    int rtk[4];
#pragma unroll
    for (int i = 0; i < 4; i++) rtk[i] = row_tok[row0 + (t >> 3) + i * 32];

    float4 ar[4][2];                      // A prefetch regs
    float4 br[2][4];                      // B prefetch regs

#define F1_LOADA(kc)                                                         \
    {                                                                        \
        _Pragma("unroll") for (int i = 0; i < 4; i++) {                      \
            if (rtk[i] >= 0) {                                               \
                const float* g = xs + (size_t)rtk[i] * IDIM + (kc) * BK + k8;\
                ar[i][0] = *(const float4*)g;                                \
                ar[i][1] = *(const float4*)(g + 4);                          \
            } else {                                                         \
                ar[i][0] = make_float4(0.f, 0.f, 0.f, 0.f);                  \
                ar[i][1] = make_float4(0.f, 0.f, 0.f, 0.f);                  \
            }                                                                \
        }                                                                    \
    }
#define F1_LOADB(kc)                                                         \
    {                                                                        \
        _Pragma("unroll") for (int i = 0; i < 2; i++) {                      \
            int kp = kp0 + i * 16;                                           \
            const float* g = Be + (size_t)((kc) * BK + 2 * kp) * HID + n0g + noct0 * 8; \
            br[i][0] = *(const float4*)g;                                    \
            br[i][1] = *(const float4*)(g + 4);                              \
            br[i][2] = *(const float4*)(g + HID);                            \
            br[i][3] = *(const float4*)(g + HID + 4);                        \
        }                                                                    \
    }
#define F1_WRITEA()                                                          \
    {                                                                        \
        _Pragma("unroll") for (int i = 0; i < 4; i++) {                      \
            int rowA = (t >> 3) + i * 32;                                    \
            *(uint4*)&sA[rowA * BK + k8] = pack8(ar[i][0], ar[i][1]);        \
        }                                                                    \
    }
#define F1_WRITEB(buf)                                                       \
    {                                                                        \
        _Pragma("unroll") for (int i = 0; i < 2; i++) {                      \
            int kp = kp0 + i * 16;                                           \
            float a0[8] = {br[i][0].x, br[i][0].y, br[i][0].z, br[i][0].w,   \
                           br[i][1].x, br[i][1].y, br[i][1].z, br[i][1].w};  \
            float a1[8] = {br[i][2].x, br[i][2].y, br[i][2].z, br[i][2].w,   \
                           br[i][3].x, br[i][3].y, br[i][3].z, br[i][3].w};  \
            int kswz = (2 * kp) ^ ((noct0 & 3) * 16);                        \
            int hwb  = noct0 * 8 * 72 + kswz;                                \
            _Pragma("unroll") for (int j = 0; j < 8; j++)                    \
                *(uint32_t*)&sB[buf][hwb + j * 72] = pack2(a0[j], a1[j]);    \
        }                                                                    \
    }

    f32x4 acc[4][4];
#pragma unroll
    for (int i = 0; i < 4; i++)
#pragma unroll
        for (int j = 0; j < 4; j++) acc[i][j] = (f32x4){0.f, 0.f, 0.f, 0.f};

    const int KI = IDIM / BK;
    F1_LOADA(0) F1_LOADB(0)
    F1_WRITEA() F1_WRITEB(0)
    __syncthreads();

    for (int kc = 0; kc < KI; kc++) {
        bool hn = (kc + 1 < KI);
        if (hn) { F1_LOADA(kc + 1) F1_LOADB(kc + 1) }   // issue early: MFMA covers
        const bf16* sbc = &sB[kc & 1][0];
#pragma unroll
        for (int ks = 0; ks < 2; ks++) {
            bf16x8 aF[4], bF[4];
#pragma unroll
            for (int mt = 0; mt < 4; mt++)
                aF[mt] = *(bf16x8*)&sA[(wy * 64 + mt * 16 + lm) * BK + ks * 32 + q * 8];
#pragma unroll
            for (int nt = 0; nt < 4; nt++) {
                int n  = wx * 64 + nt * 16 + lm;
                int kk = (ks * 32 + q * 8) ^ (((n >> 3) & 3) * 16);
                bF[nt] = *(bf16x8*)&sbc[n * 72 + kk];
            }
#pragma unroll
            for (int mt = 0; mt < 4; mt++)
#pragma unroll
                for (int nt = 0; nt < 4; nt++)
                    acc[mt][nt] = __builtin_amdgcn_mfma_f32_16x16x32_bf16(
                        aF[mt], bF[nt], acc[mt][nt], 0, 0, 0);
        }
        if (hn) F1_WRITEB((kc + 1) & 1)
        __syncthreads();                  // everyone done reading sA
        if (hn) F1_WRITEA()
        __syncthreads();                  // sA(kc+1) published
    }

#pragma unroll
    for (int nt = 0; nt < 4; nt++) {
        int col_l = n0l + wx * 64 + nt * 16 + lm;
        float bv  = bias_e[h0 + col_l];
#pragma unroll
        for (int mt = 0; mt < 4; mt++) {
            int rloc = wy * 64 + mt * 16 + q * 4;
#pragma unroll
            for (int r = 0; r < 4; r++) {
                float v = fmaxf(acc[mt][nt][r] + bv, 0.f);
                H[(size_t)(row0 + rloc + r) * CW + col_l] = (bf16)v;
            }
        }
    }
}

// -------- FFN2 (pipelined, split-K): out[tok] += w*(H@W2 + b2) -------------
__global__ __launch_bounds__(256, 2) void k_ffn2(const bf16* __restrict__ H,
                                                 const float* __restrict__ W2,
                                                 const float* __restrict__ b2,
                                                 const int* __restrict__ wsi,
                                                 const float* __restrict__ wsf,
                                                 float* __restrict__ out,
                                                 int h0, int CW, int addb) {
    int ntiles = wsi[WS_NTILES / 4];
    int tile = blockIdx.y;
    if (tile >= ntiles) return;
    int e    = wsi[WS_TILE_E / 4 + tile];
    int row0 = wsi[WS_TILE_R / 4 + tile];
    int n0   = blockIdx.x * BN;
    int kw   = CW / gridDim.z;
    int kb   = blockIdx.z * kw;

    const int*   row_tok = wsi + WS_ROW_TOK / 4;
    const float* row_w   = wsf + WS_ROW_W / 4;
    const float* Be      = W2 + (size_t)e * HID * IDIM;
    const float* bias_e  = b2 + (size_t)e * IDIM;

    __shared__ bf16 sA[BM * BK];
    __shared__ bf16 sB[2][BNS];

    int t    = threadIdx.x;
    int lane = t & 63, wv = t >> 6;
    int wx = wv & 1, wy = wv >> 1;
    int lm = lane & 15, q = lane >> 4;
    int noct0 = t & 15, kp0 = t >> 4;
    int k8 = (t & 7) * 8;

    uint4  ar[4];
    float4 br[2][4];

#define F2_LOADA(kc)                                                         \
    {                                                                        \
        _Pragma("unroll") for (int i = 0; i < 4; i++) {                      \
            int rowA = (t >> 3) + i * 32;                                    \
            ar[i] = *(const uint4*)&H[(size_t)(row0 + rowA) * CW + kb + (kc) * BK + k8]; \
        }                                                                    \
    }
#define F2_LOADB(kc)                                                         \
    {                                                                        \
        _Pragma("unroll") for (int i = 0; i < 2; i++) {                      \
            int kp = kp0 + i * 16;                                           \
            const float* g = Be + (size_t)(h0 + kb + (kc) * BK + 2 * kp) * IDIM + n0 + noct0 * 8; \
            br[i][0] = *(const float4*)g;                                    \
            br[i][1] = *(const float4*)(g + 4);                              \
            br[i][2] = *(const float4*)(g + IDIM);                           \
            br[i][3] = *(const float4*)(g + IDIM + 4);                       \
        }                                                                    \
    }
#define F2_WRITEA()                                                          \
    {                                                                        \
        _Pragma("unroll") for (int i = 0; i < 4; i++) {                      \
            int rowA = (t >> 3) + i * 32;                                    \
            *(uint4*)&sA[rowA * BK + k8] = ar[i];                            \
        }                                                                    \
    }
#define F2_WRITEB(buf)                                                       \
    {                                                                        \
        _Pragma("unroll") for (int i = 0; i < 2; i++) {                      \
            int kp = kp0 + i * 16;                                           \
            float a0[8] = {br[i][0].x, br[i][0].y, br[i][0].z, br[i][0].w,   \
                           br[i][1].x, br[i][1].y, br[i][1].z, br[i][1].w};  \
            float a1[8] = {br[i][2].x, br[i][2].y, br[i][2].z, br[i][2].w,   \
                           br[i][3].x, br[i][3].y, br[i][3].z, br[i][3].w};  \
            int kswz = (2 * kp) ^ ((noct0 & 3) * 16);                        \
            int hwb  = noct0 * 8 * 72 + kswz;                                \
            _Pragma("unroll") for (int j = 0; j < 8; j++)                    \
                *(uint32_t*)&sB[buf][hwb + j * 72] = pack2(a0[j], a1[j]);    \
        }                                                                    \
    }

    f32x4 acc[4][4];
#pragma unroll
    for (int i = 0; i < 4; i++)
#pragma unroll
        for (int j = 0; j < 4; j++) acc[i][j] = (f32x4){0.f, 0.f, 0.f, 0.f};

    const int KI = kw / BK;
    F2_LOADA(0) F2_LOADB(0)
    F2_WRITEA() F2_WRITEB(0)
    __syncthreads();

    for (int kc = 0; kc < KI; kc++) {
        bool hn = (kc + 1 < KI);
        if (hn) { F2_LOADA(kc + 1) F2_LOADB(kc + 1) }
        const bf16* sbc = &sB[kc & 1][0];
#pragma unroll
        for (int ks = 0; ks < 2; ks++) {
            bf16x8 aF[4], bF[4];
#pragma unroll
            for (int mt = 0; mt < 4; mt++)
                aF[mt] = *(bf16x8*)&sA[(wy * 64 + mt * 16 + lm) * BK + ks * 32 + q * 8];
#pragma unroll
            for (int nt = 0; nt < 4; nt++) {
                int n  = wx * 64 + nt * 16 + lm;
                int kk = (ks * 32 + q * 8) ^ (((n >> 3) & 3) * 16);
                bF[nt] = *(bf16x8*)&sbc[n * 72 + kk];
            }
#pragma unroll
            for (int mt = 0; mt < 4; mt++)
#pragma unroll
                for (int nt = 0; nt < 4; nt++)
                    acc[mt][nt] = __builtin_amdgcn_mfma_f32_16x16x32_bf16(
                        aF[mt], bF[nt], acc[mt][nt], 0, 0, 0);
        }
        if (hn) F2_WRITEB((kc + 1) & 1)
        __syncthreads();
        if (hn) F2_WRITEA()
        __syncthreads();
    }

    // epilogue: weighted atomic add (bias only from z==0 of chunk 0)
    int   tokr[16];
    float wr[16];
#pragma unroll
    for (int mt = 0; mt < 4; mt++)
#pragma unroll
        for (int r = 0; r < 4; r++) {
            int rg = row0 + wy * 64 + mt * 16 + q * 4 + r;
            tokr[mt * 4 + r] = row_tok[rg];
            wr[mt * 4 + r]   = row_w[rg];
        }
    int dobias = addb && (blockIdx.z == 0);
#pragma unroll
    for (int nt = 0; nt < 4; nt++) {
        int col  = n0 + wx * 64 + nt * 16 + lm;
        float bv = dobias ? bias_e[col] : 0.f;
#pragma unroll
        for (int mt = 0; mt < 4; mt++)
#pragma unroll
            for (int r = 0; r < 4; r++) {
                int tok = tokr[mt * 4 + r];
                if (tok >= 0)
                    atomicAdd(&out[(size_t)tok * IDIM + col],
                              wr[mt * 4 + r] * (acc[mt][nt][r] + bv));
            }
    }
}

// ---------------- zero-workspace fallback (fp32) ----------------
__global__ __launch_bounds__(256) void k_fallback(const float* __restrict__ xs,
                                                  const float* __restrict__ Wg,
                                                  const float* __restrict__ W1,
                                                  const float* __restrict__ b1,
                                                  const float* __restrict__ W2,
                                                  const float* __restrict__ b2,
                                                  float* __restrict__ out) {
    __shared__ float xbuf[IDIM];
    __shared__ float hbuf[256];
    __shared__ float slog[NE];
    __shared__ int   sel[2];
    __shared__ float selw[2];

    int t   = blockIdx.x;
    int tid = threadIdx.x;

    for (int i = tid; i < IDIM; i += 256)
        xbuf[i] = xs[(size_t)t * IDIM + i];
    __syncthreads();
    {
        int e = tid >> 5, l = tid & 31;
        float p = 0.f;
        for (int d = l; d < IDIM; d += 32)
            p += xbuf[d] * Wg[e * IDIM + d];
        for (int off = 16; off > 0; off >>= 1) p += __shfl_down(p, off, 32);
        if (l == 0) slog[e] = p;
    }
    __syncthreads();
    if (tid == 0) {
        int e0 = 0; float l0 = slog[0];
        for (int e = 1; e < NE; e++) if (slog[e] > l0) { l0 = slog[e]; e0 = e; }
        int e1 = -1; float l1 = -1e30f;
        for (int e = 0; e < NE; e++) if (e != e0 && slog[e] > l1) { l1 = slog[e]; e1 = e; }
        if (e1 < 0) e1 = (e0 + 1) & 7;
        float z = __expf(l1 - l0);
        sel[0] = e0; sel[1] = e1;
        selw[0] = 1.f / (1.f + z);
        selw[1] = z / (1.f + z);
    }
    __syncthreads();

    float ytot[4] = {0.f, 0.f, 0.f, 0.f};
#pragma unroll
    for (int s = 0; s < 2; s++) {
        int   e = sel[s];
        float w = selw[s];
        const float* W1e = W1 + (size_t)e * IDIM * HID;
        const float* W2e = W2 + (size_t)e * HID * IDIM;
        float ys[4] = {0.f, 0.f, 0.f, 0.f};
        for (int hb = 0; hb < HID / 256; hb++) {
            int h = hb * 256 + tid;
            float acc = b1[e * HID + h];
            for (int d = 0; d < IDIM; d++)
                acc += xbuf[d] * W1e[(size_t)d * HID + h];
            __syncthreads();
            hbuf[tid] = fmaxf(acc, 0.f);
            __syncthreads();
            for (int hh = 0; hh < 256; hh++) {
                float hv = hbuf[hh];
                const float* wrow = W2e + (size_t)(hb * 256 + hh) * IDIM;
#pragma unroll
                for (int cc = 0; cc < 4; cc++)
                    ys[cc] += hv * wrow[cc * 256 + tid];
            }
        }
#pragma unroll
        for (int cc = 0; cc < 4; cc++)
            ytot[cc] += w * (ys[cc] + b2[e * IDIM + cc * 256 + tid]);
    }
#pragma unroll
    for (int cc = 0; cc < 4; cc++)
        out[(size_t)t * IDIM + cc * 256 + tid] = ytot[cc];
}

extern "C" void kernel_launch(void* const* d_in, const int* in_sizes, int n_in,
                              void* d_out, int out_size, void* d_ws, size_t ws_size,
                              hipStream_t stream) {
    int o = (n_in >= 7 && in_sizes[1] == 1) ? 1 : 0;
    const float* xs = (const float*)d_in[0];
    const float* Wg = (const float*)d_in[1 + o];
    const float* W1 = (const float*)d_in[2 + o];
    const float* b1 = (const float*)d_in[3 + o];
    const float* W2 = (const float*)d_in[4 + o];
    const float* b2 = (const float*)d_in[5 + o];
    float* out = (float*)d_out;

    if (ws_size < WS_MIN_FAST || d_ws == nullptr) {
        k_fallback<<<T_TOK, 256, 0, stream>>>(xs, Wg, W1, b1, W2, b2, out);
        return;
    }

    char*  ws  = (char*)d_ws;
    int*   wsi = (int*)d_ws;
    float* wsf = (float*)d_ws;
    bf16*  H   = (bf16*)(ws + WS_H);

    int HC = 1;
    while (HC < 32 &&
           (size_t)WS_H + (size_t)RMAX * (HID / HC) * 2 > ws_size)
        HC <<= 1;
    int CW = HID / HC;
    int SK = 4;                            // split-K for ffn2
    while (CW / SK < BK) SK >>= 1;

    k_router<<<T_TOK / 4, 256, 0, stream>>>(xs, Wg, wsi + WS_TOK_E / 4,
                                            wsf + WS_TOK_W / 4, (float4*)out);
    k_setup<<<1, 256, 0, stream>>>(wsi, wsf);

    for (int c = 0; c < HC; c++) {
        k_ffn1<<<dim3(CW / BN, MAXTILES), 256, 0, stream>>>(
            xs, W1, b1, wsi, H, c * CW, CW);
        k_ffn2<<<dim3(IDIM / BN, MAXTILES, SK), 256, 0, stream>>>(
            H, W2, b2, wsi, wsf, out, c * CW, CW, c == 0 ? 1 : 0);
    }
}